// Round 20
// baseline (784.236 us; speedup 1.0000x reference)
//
#include <hip/hip_runtime.h>
#include <hip/hip_bf16.h>

// Model dims: B=16, N=2048, F=40, D=256, H=8, K=256, L=4, DH=32
// fp32 inputs/outputs; bf16 MFMA GEMMs + attention; bf16 residual stream h.
// gemm64: 64x64 tile, BK=64, XOR slot-swizzle, 8 blocks/CU, COMPILE-TIME K
// (full unroll -> global_load_lds literal offsets, no loop-carried addr VALU).
// gemm_qap merges q+apkv; gemm_kv merges kp+vpT; ln_tr fuses LN+transpose.

typedef short bf16x8 __attribute__((ext_vector_type(8)));
typedef float f32x4 __attribute__((ext_vector_type(4)));
typedef unsigned int u32x4 __attribute__((ext_vector_type(4)));

#define GLOBAL_AS __attribute__((address_space(1)))
#define LDS_AS __attribute__((address_space(3)))

static __device__ __forceinline__ float gelu_f(float v) {
    const float u2 = v * (0.7978845608028654f + 0.03567740814183427f * v * v);
    const float t = 1.0f - 2.0f / (__expf(2.0f * u2) + 1.0f);
    return 0.5f * v * (1.0f + t);
}
static __device__ __forceinline__ ushort f2bf(float x) {
    __hip_bfloat16 h = __float2bfloat16(x);
    return __builtin_bit_cast(ushort, h);
}
static __device__ __forceinline__ float bf2f(ushort u) {
    unsigned int x = ((unsigned int)u) << 16;
    return __builtin_bit_cast(float, x);
}

// ---------------- embed + pos + LN0: 32 rows/block, 8 rows/wave, bf16 out ----------------
__global__ __launch_bounds__(256)
void embed_ln3(const float* __restrict__ x, const float* __restrict__ Wemb,
               const float* __restrict__ bemb, const float* __restrict__ pos,
               const float* __restrict__ g0, const float* __restrict__ b0,
               ushort* __restrict__ H)
{
    __shared__ float xs[32][40];
    const int t = threadIdx.x, w = t >> 6, l = t & 63;
    const long row0 = (long)blockIdx.x * 32;
    for (int idx = t; idx < 32 * 40; idx += 256)
        ((float*)xs)[idx] = x[row0 * 40 + idx];
    __syncthreads();

    const int r0 = w * 8;
    const int nbase = (int)((row0 + r0) & 2047);
    const float4 be = *(const float4*)&bemb[l * 4];
    float4 acc[8];
    #pragma unroll 8
    for (int j = 0; j < 8; ++j) {
        const float4 pv = *(const float4*)&pos[(long)(nbase + j) * 256 + l * 4];
        acc[j].x = be.x + pv.x; acc[j].y = be.y + pv.y;
        acc[j].z = be.z + pv.z; acc[j].w = be.w + pv.w;
    }
    for (int f = 0; f < 40; ++f) {
        const float4 wv = *(const float4*)&Wemb[f * 256 + l * 4];
        #pragma unroll 8
        for (int j = 0; j < 8; ++j) {
            const float xf = xs[r0 + j][f];
            acc[j].x += xf * wv.x; acc[j].y += xf * wv.y;
            acc[j].z += xf * wv.z; acc[j].w += xf * wv.w;
        }
    }
    const float4 gv = *(const float4*)&g0[l * 4];
    const float4 bv = *(const float4*)&b0[l * 4];
    #pragma unroll 8
    for (int j = 0; j < 8; ++j) {
        float s = acc[j].x + acc[j].y + acc[j].z + acc[j].w;
        #pragma unroll
        for (int m = 32; m >= 1; m >>= 1) s += __shfl_xor(s, m);
        const float mean = s * (1.0f / 256.0f);
        const float dx = acc[j].x - mean, dy = acc[j].y - mean;
        const float dz = acc[j].z - mean, dw = acc[j].w - mean;
        float q = dx * dx + dy * dy + dz * dz + dw * dw;
        #pragma unroll
        for (int m = 32; m >= 1; m >>= 1) q += __shfl_xor(q, m);
        const float inv = rsqrtf(q * (1.0f / 256.0f) + 1e-5f);
        ushort4 y;
        y.x = f2bf(dx * inv * gv.x + bv.x);
        y.y = f2bf(dy * inv * gv.y + bv.y);
        y.z = f2bf(dz * inv * gv.z + bv.z);
        y.w = f2bf(dw * inv * gv.w + bv.w);
        *(ushort4*)&H[(row0 + r0 + j) * 256 + l * 4] = y;
    }
}

// ---------------- LayerNorm bf16 -> bf16 (for LN2) ----------------
__global__ __launch_bounds__(256)
void ln_bf(const ushort* __restrict__ X, const float* __restrict__ g,
           const float* __restrict__ b, ushort* __restrict__ Y)
{
    const int row = blockIdx.x * 4 + (threadIdx.x >> 6);
    const int lane = threadIdx.x & 63;
    const long base = (long)row * 256 + lane * 4;
    const ushort4 xu = *(const ushort4*)&X[base];
    float4 xv;
    xv.x = bf2f(xu.x); xv.y = bf2f(xu.y); xv.z = bf2f(xu.z); xv.w = bf2f(xu.w);
    float s = xv.x + xv.y + xv.z + xv.w;
    #pragma unroll
    for (int m = 32; m >= 1; m >>= 1) s += __shfl_xor(s, m);
    const float mean = s * (1.0f / 256.0f);
    const float dx = xv.x - mean, dy = xv.y - mean, dz = xv.z - mean, dw = xv.w - mean;
    float q = dx * dx + dy * dy + dz * dz + dw * dw;
    #pragma unroll
    for (int m = 32; m >= 1; m >>= 1) q += __shfl_xor(q, m);
    const float inv = rsqrtf(q * (1.0f / 256.0f) + 1e-5f);
    const float4 gv = *(const float4*)&g[lane * 4];
    const float4 bv = *(const float4*)&b[lane * 4];
    ushort4 y;
    y.x = f2bf(dx * inv * gv.x + bv.x);
    y.y = f2bf(dy * inv * gv.y + bv.y);
    y.z = f2bf(dz * inv * gv.z + bv.z);
    y.w = f2bf(dw * inv * gv.w + bv.w);
    *(ushort4*)&Y[base] = y;
}

// ---------------- fused LayerNorm + transpose: h(bf16) -> abf + aT ----------------
__global__ __launch_bounds__(256)
void ln_tr(const ushort* __restrict__ X, const float* __restrict__ g,
           const float* __restrict__ b, ushort* __restrict__ Y,
           ushort* __restrict__ aT)
{
    __shared__ ushort tile[32 * 258];
    const int t = threadIdx.x, w = t >> 6, l = t & 63;
    const long row0 = (long)blockIdx.x * 32;
    const float4 gv = *(const float4*)&g[l * 4];
    const float4 bv = *(const float4*)&b[l * 4];
    #pragma unroll 8
    for (int j = 0; j < 8; ++j) {
        const int r = w * 8 + j;
        const long base = (row0 + r) * 256 + l * 4;
        const ushort4 xu = *(const ushort4*)&X[base];
        float4 xv;
        xv.x = bf2f(xu.x); xv.y = bf2f(xu.y); xv.z = bf2f(xu.z); xv.w = bf2f(xu.w);
        float s = xv.x + xv.y + xv.z + xv.w;
        #pragma unroll
        for (int m = 32; m >= 1; m >>= 1) s += __shfl_xor(s, m);
        const float mean = s * (1.0f / 256.0f);
        const float dx = xv.x - mean, dy = xv.y - mean, dz = xv.z - mean, dw = xv.w - mean;
        float q = dx * dx + dy * dy + dz * dz + dw * dw;
        #pragma unroll
        for (int m = 32; m >= 1; m >>= 1) q += __shfl_xor(q, m);
        const float inv = rsqrtf(q * (1.0f / 256.0f) + 1e-5f);
        ushort4 y;
        y.x = f2bf(dx * inv * gv.x + bv.x);
        y.y = f2bf(dy * inv * gv.y + bv.y);
        y.z = f2bf(dz * inv * gv.z + bv.z);
        y.w = f2bf(dw * inv * gv.w + bv.w);
        *(ushort4*)&Y[base] = y;
        *(ushort4*)&tile[r * 258 + l * 4] = y;
    }
    __syncthreads();
    const int tx = t & 31, ty = t >> 5;
    const int b_ = (int)(row0 >> 11), nn = (int)(row0 & 2047);
    #pragma unroll 8
    for (int jj = 0; jj < 32; ++jj) {
        const int c = ty * 32 + jj;
        aT[((long)(b_ * 256 + c)) * 2048 + nn + tx] = tile[tx * 258 + c];
    }
}

// ---------------- weight transpose + cast ----------------
__global__ __launch_bounds__(256)
void transpose_cast(const float* __restrict__ in, ushort* __restrict__ out,
                    int R, int C, long sIn, long sOut)
{
    __shared__ float tile[32][33];
    in += (long)blockIdx.z * sIn; out += (long)blockIdx.z * sOut;
    const int c0 = blockIdx.x * 32, r0 = blockIdx.y * 32;
    const int tx = threadIdx.x & 31, ty = threadIdx.x >> 5;
    #pragma unroll
    for (int j = 0; j < 4; ++j)
        tile[ty + j * 8][tx] = in[(long)(r0 + ty + j * 8) * C + c0 + tx];
    __syncthreads();
    #pragma unroll
    for (int j = 0; j < 4; ++j)
        out[(long)(c0 + ty + j * 8) * R + r0 + tx] = f2bf(tile[tx][ty + j * 8]);
}

// ---------------- shared gemm64 core: 64x64 tile, BK=64, compile-time K ----------
// Full unroll: global_load_lds source offsets become instruction immediates.
template<int KD, int ACT, int HASB, int ACCF>
static __device__ __forceinline__
void gemm64_core(const ushort* __restrict__ Ab, const ushort* __restrict__ Bb,
                 const float* __restrict__ bias, ushort* __restrict__ Cp,
                 int lda, int ldb, int ldc, int m0, int n0,
                 ushort* Als, ushort* Bls)
{
    const int t = threadIdx.x, l = t & 63, w = t >> 6;
    const int wr = w >> 1, wc = w & 1;
    const int fr = l & 15, fq = l >> 4;

    f32x4 acc[2][2];
    #pragma unroll
    for (int m = 0; m < 2; ++m)
        #pragma unroll
        for (int n = 0; n < 2; ++n) acc[m][n] = f32x4{0.f, 0.f, 0.f, 0.f};

    const int lrow_off = (l >> 2);
    const int lk_off = (((l & 3) ^ ((l >> 3) & 3)) * 8);
    const int c0c = 2 * w, c1c = 2 * w + 1;
    const int h0 = c0c >> 2, rb0 = (c0c & 3) * 16;
    const int h1 = c1c >> 2, rb1 = (c1c & 3) * 16;
    const ushort* Ag0 = Ab + (long)(m0 + rb0 + lrow_off) * lda + h0 * 32 + lk_off;
    const ushort* Ag1 = Ab + (long)(m0 + rb1 + lrow_off) * lda + h1 * 32 + lk_off;
    const ushort* Bg0 = Bb + (long)(n0 + rb0 + lrow_off) * ldb + h0 * 32 + lk_off;
    const ushort* Bg1 = Bb + (long)(n0 + rb1 + lrow_off) * ldb + h1 * 32 + lk_off;
    const int ad0 = h0 * 2048 + rb0 * 32, ad1 = h1 * 2048 + rb1 * 32;
    const int ks = ((fq ^ ((fr >> 1) & 3)) * 8);

    #pragma unroll
    for (int kk = 0; kk < KD; kk += 64) {
        __builtin_amdgcn_global_load_lds((const GLOBAL_AS void*)(Ag0 + kk),
                                         (LDS_AS void*)&Als[ad0], 16, 0, 0);
        __builtin_amdgcn_global_load_lds((const GLOBAL_AS void*)(Ag1 + kk),
                                         (LDS_AS void*)&Als[ad1], 16, 0, 0);
        __builtin_amdgcn_global_load_lds((const GLOBAL_AS void*)(Bg0 + kk),
                                         (LDS_AS void*)&Bls[ad0], 16, 0, 0);
        __builtin_amdgcn_global_load_lds((const GLOBAL_AS void*)(Bg1 + kk),
                                         (LDS_AS void*)&Bls[ad1], 16, 0, 0);
        __syncthreads();
        bf16x8 af[2][2], bfv[2][2];
        #pragma unroll
        for (int hh = 0; hh < 2; ++hh) {
            #pragma unroll
            for (int m = 0; m < 2; ++m)
                af[m][hh] = *(const bf16x8*)&Als[hh * 2048 + (wr * 32 + m * 16 + fr) * 32 + ks];
            #pragma unroll
            for (int n = 0; n < 2; ++n)
                bfv[n][hh] = *(const bf16x8*)&Bls[hh * 2048 + (wc * 32 + n * 16 + fr) * 32 + ks];
        }
        #pragma unroll
        for (int hh = 0; hh < 2; ++hh)
            #pragma unroll
            for (int m = 0; m < 2; ++m)
                #pragma unroll
                for (int n = 0; n < 2; ++n)
                    acc[m][n] = __builtin_amdgcn_mfma_f32_16x16x32_bf16(
                        af[m][hh], bfv[n][hh], acc[m][n], 0, 0, 0);
        __syncthreads();
    }

    float bsv[2];
    #pragma unroll
    for (int n = 0; n < 2; ++n) bsv[n] = HASB ? bias[n0 + wc * 32 + n * 16 + fr] : 0.f;
    #pragma unroll
    for (int m = 0; m < 2; ++m) {
        #pragma unroll
        for (int r = 0; r < 4; ++r) {
            const int grow = m0 + wr * 32 + m * 16 + fq * 4 + r;
            const long rowoff = (long)grow * ldc + n0 + wc * 32 + fr;
            #pragma unroll
            for (int n = 0; n < 2; ++n) {
                float v = acc[m][n][r] + bsv[n];
                if (ACT) v = gelu_f(v);
                const long off = rowoff + n * 16;
                if (ACCF) v += bf2f(Cp[off]);
                Cp[off] = f2bf(v);
            }
        }
    }
}

template<int KD, int ACT, int HASB, int ACCF>
__global__ __launch_bounds__(256)
void gemm64(const ushort* __restrict__ A, const ushort* __restrict__ BT,
            const float* __restrict__ bias, ushort* __restrict__ Cout,
            int lda, int ldb, int ldc, long sA, long sBT, long sC)
{
    __shared__ ushort Als[2 * 2048];
    __shared__ ushort Bls[2 * 2048];
    const int bz = blockIdx.z;
    gemm64_core<KD, ACT, HASB, ACCF>(A + (long)bz * sA, BT + (long)bz * sBT, bias,
                                     Cout + (long)bz * sC, lda, ldb, ldc,
                                     blockIdx.x * 64, blockIdx.y * 64, Als, Bls);
}

// merged q + apkv: grid (512, 5). y==0 -> apkv block (x -> mx,ny,b); y>0 -> q tile.
__global__ __launch_bounds__(256)
void gemm_qap(const ushort* __restrict__ abf, const ushort* __restrict__ WqT,
              ushort* __restrict__ qbf, const ushort* __restrict__ EkvT,
              const ushort* __restrict__ aT, ushort* __restrict__ apkv)
{
    __shared__ ushort Als[2 * 2048];
    __shared__ ushort Bls[2 * 2048];
    if (blockIdx.y == 0) {
        const int mx = blockIdx.x & 7, ny = (blockIdx.x >> 3) & 3, b = blockIdx.x >> 5;
        gemm64_core<2048, 0, 0, 0>(EkvT, aT + (long)b * 524288, nullptr,
                                   apkv + (long)b * 131072, 2048, 2048, 256,
                                   mx * 64, ny * 64, Als, Bls);
    } else {
        gemm64_core<256, 0, 0, 0>(abf, WqT, nullptr, qbf, 256, 256, 256,
                                  blockIdx.x * 64, (blockIdx.y - 1) * 64, Als, Bls);
    }
}

// merged kp/vpT: grid (4,4,32); z<16 -> kp[b] = apk[b]@Wk; z>=16 -> vpT[b] = Wv^T@apv[b]^T
__global__ __launch_bounds__(256)
void gemm_kv(const ushort* __restrict__ apkv, const ushort* __restrict__ WkT,
             const ushort* __restrict__ WvT, ushort* __restrict__ kp,
             ushort* __restrict__ vpT)
{
    __shared__ ushort Als[2 * 2048];
    __shared__ ushort Bls[2 * 2048];
    const int z = blockIdx.z, b = z & 15, op = z >> 4;
    const ushort* Ab; const ushort* Bb; ushort* Cp;
    if (op == 0) {
        Ab = apkv + (long)b * 131072; Bb = WkT; Cp = kp + (long)b * 65536;
    } else {
        Ab = WvT; Bb = apkv + 65536 + (long)b * 131072; Cp = vpT + (long)b * 65536;
    }
    gemm64_core<256, 0, 0, 0>(Ab, Bb, nullptr, Cp, 256, 256, 256,
                              blockIdx.x * 64, blockIdx.y * 64, Als, Bls);
}

// ---------------- fused MFMA attention, swapped-operand, P in registers ----------------
__global__ __launch_bounds__(256)
void attn_mfma2(const ushort* __restrict__ Q, const ushort* __restrict__ Kp,
                const ushort* __restrict__ VpT, ushort* __restrict__ O)
{
    __shared__ ushort Kls[256 * 40];
    __shared__ ushort Vls[32 * 264];
    const int qt = blockIdx.x, h = blockIdx.y, b = blockIdx.z;
    const int n0 = qt * 64;
    const int t = threadIdx.x, w = t >> 6, l = t & 63;
    const int fr = l & 15, fq = l >> 4;

    #pragma unroll
    for (int it = 0; it < 4; ++it) {
        const int r = (t >> 2) + it * 64, c = (t & 3) * 8;
        *(float4*)&Kls[r * 40 + c] =
            *(const float4*)&Kp[((long)(b * 256 + r)) * 256 + h * 32 + c];
    }
    {
        const int r = t >> 3, c0 = (t & 7) * 32;
        const ushort* src = VpT + ((long)(b * 256 + h * 32 + r)) * 256 + c0;
        #pragma unroll
        for (int j = 0; j < 4; ++j)
            *(float4*)&Vls[r * 264 + c0 + j * 8] = *(const float4*)(src + j * 8);
    }
    const bf16x8 bq = *(const bf16x8*)
        &Q[((long)(b * 2048 + n0 + w * 16 + fr)) * 256 + h * 32 + fq * 8];
    __syncthreads();

    f32x4 s[16];
    #pragma unroll
    for (int n = 0; n < 16; ++n) {
        const bf16x8 ak = *(const bf16x8*)&Kls[(n * 16 + fr) * 40 + fq * 8];
        s[n] = __builtin_amdgcn_mfma_f32_16x16x32_bf16(ak, bq, f32x4{0.f,0.f,0.f,0.f}, 0, 0, 0);
    }
    const float scale = 0.17677669529663687f;
    float mx = -1e30f;
    #pragma unroll
    for (int n = 0; n < 16; ++n)
        #pragma unroll
        for (int r = 0; r < 4; ++r) { s[n][r] *= scale; mx = fmaxf(mx, s[n][r]); }
    mx = fmaxf(mx, __shfl_xor(mx, 16));
    mx = fmaxf(mx, __shfl_xor(mx, 32));
    float sm = 0.f;
    unsigned int p[16][2];
    #pragma unroll
    for (int n = 0; n < 16; ++n) {
        float e0 = __expf(s[n][0] - mx), e1 = __expf(s[n][1] - mx);
        float e2 = __expf(s[n][2] - mx), e3 = __expf(s[n][3] - mx);
        sm += (e0 + e1) + (e2 + e3);
        p[n][0] = ((unsigned int)f2bf(e1) << 16) | f2bf(e0);
        p[n][1] = ((unsigned int)f2bf(e3) << 16) | f2bf(e2);
    }
    sm += __shfl_xor(sm, 16);
    sm += __shfl_xor(sm, 32);

    const int fqa = fq & 1, fqb = fq >> 1;
    f32x4 o[2] = {f32x4{0.f,0.f,0.f,0.f}, f32x4{0.f,0.f,0.f,0.f}};
    #pragma unroll
    for (int kk = 0; kk < 8; ++kk) {
        u32x4 bw;
        #pragma unroll
        for (int wd = 0; wd < 4; ++wd) {
            const int srcl = fr + ((2 * fqa + (wd >> 1)) << 4);
            const unsigned int v0 = __shfl((int)p[2 * kk][wd & 1], srcl);
            const unsigned int v1 = __shfl((int)p[2 * kk + 1][wd & 1], srcl);
            bw[wd] = fqb ? v1 : v0;
        }
        const bf16x8 breg = __builtin_bit_cast(bf16x8, bw);
        #pragma unroll
        for (int nd = 0; nd < 2; ++nd) {
            const bf16x8 av = *(const bf16x8*)&Vls[(nd * 16 + fr) * 264 + kk * 32 + fq * 8];
            o[nd] = __builtin_amdgcn_mfma_f32_16x16x32_bf16(av, breg, o[nd], 0, 0, 0);
        }
    }
    const float inv = 1.0f / sm;
    const long rowbase = ((long)(b * 2048 + n0 + w * 16 + fr)) * 256 + h * 32;
    #pragma unroll
    for (int nd = 0; nd < 2; ++nd) {
        ushort4 y;
        y.x = f2bf(o[nd][0] * inv); y.y = f2bf(o[nd][1] * inv);
        y.z = f2bf(o[nd][2] * inv); y.w = f2bf(o[nd][3] * inv);
        *(ushort4*)&O[rowbase + nd * 16 + fq * 4] = y;
    }
}

// ---------------- final head (bf16 h) ----------------
__global__ __launch_bounds__(256)
void out_kernel(const ushort* __restrict__ H, const float* __restrict__ Wout,
                const float* __restrict__ bout, float* __restrict__ out)
{
    const int row = blockIdx.x * 4 + (threadIdx.x >> 6);
    const int lane = threadIdx.x & 63;
    const ushort4 hu = *(const ushort4*)&H[(long)row * 256 + lane * 4];
    float4 wv = *(const float4*)&Wout[lane * 4];
    float s = bf2f(hu.x) * wv.x + bf2f(hu.y) * wv.y +
              bf2f(hu.z) * wv.z + bf2f(hu.w) * wv.w;
    #pragma unroll
    for (int m = 32; m >= 1; m >>= 1) s += __shfl_xor(s, m);
    if (lane == 0) out[row] = s + bout[0];
}

extern "C" void kernel_launch(void* const* d_in, const int* in_sizes, int n_in,
                              void* d_out, int out_size, void* d_ws, size_t ws_size,
                              hipStream_t stream)
{
    const float* x    = (const float*)d_in[0];
    const float* Wemb = (const float*)d_in[1];
    const float* bemb = (const float*)d_in[2];
    const float* pos  = (const float*)d_in[3];
    const float* ln0g = (const float*)d_in[4];
    const float* ln0b = (const float*)d_in[5];
    const float* ln1g = (const float*)d_in[6];
    const float* ln1b = (const float*)d_in[7];
    const float* Wq   = (const float*)d_in[8];
    const float* Wk   = (const float*)d_in[9];
    const float* Wv   = (const float*)d_in[10];
    const float* Ek   = (const float*)d_in[11];
    const float* Ev   = (const float*)d_in[12];
    const float* Wo   = (const float*)d_in[13];
    const float* bo   = (const float*)d_in[14];
    const float* ln2g = (const float*)d_in[15];
    const float* ln2b = (const float*)d_in[16];
    const float* W1   = (const float*)d_in[17];
    const float* b1   = (const float*)d_in[18];
    const float* W2   = (const float*)d_in[19];
    const float* b2   = (const float*)d_in[20];
    const float* Wout = (const float*)d_in[21];
    const float* bout = (const float*)d_in[22];

    char* ws = (char*)d_ws;
    ushort* h    = (ushort*)(ws + 0);                  // bf16 [32768,256]
    ushort* abf  = (ushort*)(ws + 33554432L);
    ushort* aT   = (ushort*)(ws + 50331648L);
    ushort* kp   = (ushort*)(ws + 67108864L);
    ushort* vpT  = (ushort*)(ws + 69206016L);
    ushort* apkv = (ushort*)(ws + 71303168L);
    ushort* qbf  = (ushort*)(ws + 100663296L);
    ushort* hid  = (ushort*)(ws + 50331648L);
    ushort* WT   = (ushort*)(ws + 117440512L);
    ushort* WqT  = WT;
    ushort* WkT  = WT + 262144;
    ushort* WvT  = WT + 524288;
    ushort* WoT  = WT + 786432;
    ushort* W1T  = WT + 1048576;
    ushort* W2T  = WT + 2097152;
    ushort* EkvT = WT + 3145728;
    float* outp = (float*)d_out;

    transpose_cast<<<dim3(8, 8, 4), 256, 0, stream>>>(Wq, WqT, 256, 256, 65536, 65536);
    transpose_cast<<<dim3(8, 8, 4), 256, 0, stream>>>(Wk, WkT, 256, 256, 65536, 65536);
    transpose_cast<<<dim3(8, 8, 4), 256, 0, stream>>>(Wv, WvT, 256, 256, 65536, 65536);
    transpose_cast<<<dim3(8, 8, 4), 256, 0, stream>>>(Wo, WoT, 256, 256, 65536, 65536);
    transpose_cast<<<dim3(32, 8, 4), 256, 0, stream>>>(W1, W1T, 256, 1024, 262144, 262144);
    transpose_cast<<<dim3(8, 32, 4), 256, 0, stream>>>(W2, W2T, 1024, 256, 262144, 262144);
    transpose_cast<<<dim3(8, 64, 4), 256, 0, stream>>>(Ek, EkvT, 2048, 256, 524288, 1048576);
    transpose_cast<<<dim3(8, 64, 4), 256, 0, stream>>>(Ev, EkvT + 524288, 2048, 256, 524288, 1048576);

    embed_ln3<<<1024, 256, 0, stream>>>(x, Wemb, bemb, pos, ln0g, ln0b, h);
    ln_tr<<<1024, 256, 0, stream>>>(h, ln1g, ln1b, abf, aT);

    for (int i = 0; i < 4; ++i) {
        const ushort* WqT_i = WqT + i * 65536;
        const ushort* WkT_i = WkT + i * 65536;
        const ushort* WvT_i = WvT + i * 65536;
        const ushort* WoT_i = WoT + i * 65536;
        const ushort* W1T_i = W1T + i * 262144;
        const ushort* W2T_i = W2T + i * 262144;
        const ushort* EkvT_i = EkvT + (long)i * 1048576;

        // q = a@Wq  and  apkv[b] = [Ek^T;Ev^T]@a[b] — merged dispatch
        gemm_qap<<<dim3(512, 5, 1), 256, 0, stream>>>(abf, WqT_i, qbf, EkvT_i, aT, apkv);
        // kp[b] = apk[b]@Wk  and  vpT[b] = Wv^T@apv[b]^T — merged dispatch
        gemm_kv<<<dim3(4, 4, 32), 256, 0, stream>>>(apkv, WkT_i, WvT_i, kp, vpT);
        // fused MFMA attention -> abf
        attn_mfma2<<<dim3(32, 8, 16), 256, 0, stream>>>(qbf, kp, vpT, abf);
        // h += attnout @ Wo + bo (bf16 RMW)
        gemm64<256,0,1,1><<<dim3(512, 4, 1), 256, 0, stream>>>(abf, WoT_i, bo + i * 256, h,
            256, 256, 256, 0, 0, 0);
        // abf = LN2(h)
        ln_bf<<<8192, 256, 0, stream>>>(h, ln2g + i * 256, ln2b + i * 256, abf);
        // hid = gelu(a @ W1 + b1)
        gemm64<256,1,1,0><<<dim3(512, 16, 1), 256, 0, stream>>>(abf, W1T_i,
            b1 + (long)i * 1024, hid, 256, 256, 1024, 0, 0, 0);
        // h += hid @ W2 + b2 (bf16 RMW)
        gemm64<1024,0,1,1><<<dim3(512, 4, 1), 256, 0, stream>>>(hid, W2T_i, b2 + i * 256, h,
            1024, 1024, 256, 0, 0, 0);
        if (i < 3)
            ln_tr<<<1024, 256, 0, stream>>>(h, ln1g + (i + 1) * 256,
                ln1b + (i + 1) * 256, abf, aT);
    }
    out_kernel<<<8192, 256, 0, stream>>>(h, Wout, bout, outp);
}

// Round 21
// 776.321 us; speedup vs baseline: 1.0102x; 1.0102x over previous
//
#include <hip/hip_runtime.h>
#include <hip/hip_bf16.h>

// Model dims: B=16, N=2048, F=40, D=256, H=8, K=256, L=4, DH=32
// fp32 inputs/outputs; bf16 MFMA GEMMs + attention; bf16 residual stream h.
// gemm64: 64x64 tile, BK=64, XOR slot-swizzle (conflict-free), 8 blocks/CU.
// gemm_qap merges the q and apkv GEMMs (independent) into one dispatch;
// gemm_kv merges kp and vpT. ln_tr fuses LayerNorm with the activation transpose.

typedef short bf16x8 __attribute__((ext_vector_type(8)));
typedef float f32x4 __attribute__((ext_vector_type(4)));
typedef unsigned int u32x4 __attribute__((ext_vector_type(4)));

#define GLOBAL_AS __attribute__((address_space(1)))
#define LDS_AS __attribute__((address_space(3)))

static __device__ __forceinline__ float gelu_f(float v) {
    const float u2 = v * (0.7978845608028654f + 0.03567740814183427f * v * v);
    const float t = 1.0f - 2.0f / (__expf(2.0f * u2) + 1.0f);
    return 0.5f * v * (1.0f + t);
}
static __device__ __forceinline__ ushort f2bf(float x) {
    __hip_bfloat16 h = __float2bfloat16(x);
    return __builtin_bit_cast(ushort, h);
}
static __device__ __forceinline__ float bf2f(ushort u) {
    unsigned int x = ((unsigned int)u) << 16;
    return __builtin_bit_cast(float, x);
}

// ---------------- embed + pos + LN0: 32 rows/block, 8 rows/wave, bf16 out ----------------
__global__ __launch_bounds__(256)
void embed_ln3(const float* __restrict__ x, const float* __restrict__ Wemb,
               const float* __restrict__ bemb, const float* __restrict__ pos,
               const float* __restrict__ g0, const float* __restrict__ b0,
               ushort* __restrict__ H)
{
    __shared__ float xs[32][40];
    const int t = threadIdx.x, w = t >> 6, l = t & 63;
    const long row0 = (long)blockIdx.x * 32;
    for (int idx = t; idx < 32 * 40; idx += 256)
        ((float*)xs)[idx] = x[row0 * 40 + idx];
    __syncthreads();

    const int r0 = w * 8;
    const int nbase = (int)((row0 + r0) & 2047);
    const float4 be = *(const float4*)&bemb[l * 4];
    float4 acc[8];
    #pragma unroll 8
    for (int j = 0; j < 8; ++j) {
        const float4 pv = *(const float4*)&pos[(long)(nbase + j) * 256 + l * 4];
        acc[j].x = be.x + pv.x; acc[j].y = be.y + pv.y;
        acc[j].z = be.z + pv.z; acc[j].w = be.w + pv.w;
    }
    for (int f = 0; f < 40; ++f) {
        const float4 wv = *(const float4*)&Wemb[f * 256 + l * 4];
        #pragma unroll 8
        for (int j = 0; j < 8; ++j) {
            const float xf = xs[r0 + j][f];
            acc[j].x += xf * wv.x; acc[j].y += xf * wv.y;
            acc[j].z += xf * wv.z; acc[j].w += xf * wv.w;
        }
    }
    const float4 gv = *(const float4*)&g0[l * 4];
    const float4 bv = *(const float4*)&b0[l * 4];
    #pragma unroll 8
    for (int j = 0; j < 8; ++j) {
        float s = acc[j].x + acc[j].y + acc[j].z + acc[j].w;
        #pragma unroll
        for (int m = 32; m >= 1; m >>= 1) s += __shfl_xor(s, m);
        const float mean = s * (1.0f / 256.0f);
        const float dx = acc[j].x - mean, dy = acc[j].y - mean;
        const float dz = acc[j].z - mean, dw = acc[j].w - mean;
        float q = dx * dx + dy * dy + dz * dz + dw * dw;
        #pragma unroll
        for (int m = 32; m >= 1; m >>= 1) q += __shfl_xor(q, m);
        const float inv = rsqrtf(q * (1.0f / 256.0f) + 1e-5f);
        ushort4 y;
        y.x = f2bf(dx * inv * gv.x + bv.x);
        y.y = f2bf(dy * inv * gv.y + bv.y);
        y.z = f2bf(dz * inv * gv.z + bv.z);
        y.w = f2bf(dw * inv * gv.w + bv.w);
        *(ushort4*)&H[(row0 + r0 + j) * 256 + l * 4] = y;
    }
}

// ---------------- LayerNorm bf16 -> bf16 (for LN2) ----------------
__global__ __launch_bounds__(256)
void ln_bf(const ushort* __restrict__ X, const float* __restrict__ g,
           const float* __restrict__ b, ushort* __restrict__ Y)
{
    const int row = blockIdx.x * 4 + (threadIdx.x >> 6);
    const int lane = threadIdx.x & 63;
    const long base = (long)row * 256 + lane * 4;
    const ushort4 xu = *(const ushort4*)&X[base];
    float4 xv;
    xv.x = bf2f(xu.x); xv.y = bf2f(xu.y); xv.z = bf2f(xu.z); xv.w = bf2f(xu.w);
    float s = xv.x + xv.y + xv.z + xv.w;
    #pragma unroll
    for (int m = 32; m >= 1; m >>= 1) s += __shfl_xor(s, m);
    const float mean = s * (1.0f / 256.0f);
    const float dx = xv.x - mean, dy = xv.y - mean, dz = xv.z - mean, dw = xv.w - mean;
    float q = dx * dx + dy * dy + dz * dz + dw * dw;
    #pragma unroll
    for (int m = 32; m >= 1; m >>= 1) q += __shfl_xor(q, m);
    const float inv = rsqrtf(q * (1.0f / 256.0f) + 1e-5f);
    const float4 gv = *(const float4*)&g[lane * 4];
    const float4 bv = *(const float4*)&b[lane * 4];
    ushort4 y;
    y.x = f2bf(dx * inv * gv.x + bv.x);
    y.y = f2bf(dy * inv * gv.y + bv.y);
    y.z = f2bf(dz * inv * gv.z + bv.z);
    y.w = f2bf(dw * inv * gv.w + bv.w);
    *(ushort4*)&Y[base] = y;
}

// ---------------- fused LayerNorm + transpose: h(bf16) -> abf + aT ----------------
__global__ __launch_bounds__(256)
void ln_tr(const ushort* __restrict__ X, const float* __restrict__ g,
           const float* __restrict__ b, ushort* __restrict__ Y,
           ushort* __restrict__ aT)
{
    __shared__ ushort tile[32 * 258];
    const int t = threadIdx.x, w = t >> 6, l = t & 63;
    const long row0 = (long)blockIdx.x * 32;
    const float4 gv = *(const float4*)&g[l * 4];
    const float4 bv = *(const float4*)&b[l * 4];
    #pragma unroll 8
    for (int j = 0; j < 8; ++j) {
        const int r = w * 8 + j;
        const long base = (row0 + r) * 256 + l * 4;
        const ushort4 xu = *(const ushort4*)&X[base];
        float4 xv;
        xv.x = bf2f(xu.x); xv.y = bf2f(xu.y); xv.z = bf2f(xu.z); xv.w = bf2f(xu.w);
        float s = xv.x + xv.y + xv.z + xv.w;
        #pragma unroll
        for (int m = 32; m >= 1; m >>= 1) s += __shfl_xor(s, m);
        const float mean = s * (1.0f / 256.0f);
        const float dx = xv.x - mean, dy = xv.y - mean, dz = xv.z - mean, dw = xv.w - mean;
        float q = dx * dx + dy * dy + dz * dz + dw * dw;
        #pragma unroll
        for (int m = 32; m >= 1; m >>= 1) q += __shfl_xor(q, m);
        const float inv = rsqrtf(q * (1.0f / 256.0f) + 1e-5f);
        ushort4 y;
        y.x = f2bf(dx * inv * gv.x + bv.x);
        y.y = f2bf(dy * inv * gv.y + bv.y);
        y.z = f2bf(dz * inv * gv.z + bv.z);
        y.w = f2bf(dw * inv * gv.w + bv.w);
        *(ushort4*)&Y[base] = y;
        *(ushort4*)&tile[r * 258 + l * 4] = y;
    }
    __syncthreads();
    const int tx = t & 31, ty = t >> 5;
    const int b_ = (int)(row0 >> 11), nn = (int)(row0 & 2047);
    #pragma unroll 8
    for (int jj = 0; jj < 32; ++jj) {
        const int c = ty * 32 + jj;
        aT[((long)(b_ * 256 + c)) * 2048 + nn + tx] = tile[tx * 258 + c];
    }
}

// ---------------- weight transpose + cast ----------------
__global__ __launch_bounds__(256)
void transpose_cast(const float* __restrict__ in, ushort* __restrict__ out,
                    int R, int C, long sIn, long sOut)
{
    __shared__ float tile[32][33];
    in += (long)blockIdx.z * sIn; out += (long)blockIdx.z * sOut;
    const int c0 = blockIdx.x * 32, r0 = blockIdx.y * 32;
    const int tx = threadIdx.x & 31, ty = threadIdx.x >> 5;
    #pragma unroll
    for (int j = 0; j < 4; ++j)
        tile[ty + j * 8][tx] = in[(long)(r0 + ty + j * 8) * C + c0 + tx];
    __syncthreads();
    #pragma unroll
    for (int j = 0; j < 4; ++j)
        out[(long)(c0 + ty + j * 8) * R + r0 + tx] = f2bf(tile[tx][ty + j * 8]);
}

// ---------------- shared gemm64 core: 64x64 tile, BK=64, XOR slot-swizzle ----------
template<int ACT, int HASB, int ACCF>
static __device__ __forceinline__
void gemm64_core(const ushort* __restrict__ Ab, const ushort* __restrict__ Bb,
                 const float* __restrict__ bias, ushort* __restrict__ Cp,
                 int Kd, int lda, int ldb, int ldc, int m0, int n0,
                 ushort* Als, ushort* Bls)
{
    const int t = threadIdx.x, l = t & 63, w = t >> 6;
    const int wr = w >> 1, wc = w & 1;
    const int fr = l & 15, fq = l >> 4;

    f32x4 acc[2][2];
    #pragma unroll
    for (int m = 0; m < 2; ++m)
        #pragma unroll
        for (int n = 0; n < 2; ++n) acc[m][n] = f32x4{0.f, 0.f, 0.f, 0.f};

    const int lrow_off = (l >> 2);
    const int lk_off = (((l & 3) ^ ((l >> 3) & 3)) * 8);
    const int c0c = 2 * w, c1c = 2 * w + 1;
    const int h0 = c0c >> 2, rb0 = (c0c & 3) * 16;
    const int h1 = c1c >> 2, rb1 = (c1c & 3) * 16;
    const ushort* Ag0 = Ab + (long)(m0 + rb0 + lrow_off) * lda + h0 * 32 + lk_off;
    const ushort* Ag1 = Ab + (long)(m0 + rb1 + lrow_off) * lda + h1 * 32 + lk_off;
    const ushort* Bg0 = Bb + (long)(n0 + rb0 + lrow_off) * ldb + h0 * 32 + lk_off;
    const ushort* Bg1 = Bb + (long)(n0 + rb1 + lrow_off) * ldb + h1 * 32 + lk_off;
    const int ad0 = h0 * 2048 + rb0 * 32, ad1 = h1 * 2048 + rb1 * 32;
    const int ks = ((fq ^ ((fr >> 1) & 3)) * 8);

    for (int kk = 0; kk < Kd; kk += 64) {
        __builtin_amdgcn_global_load_lds((const GLOBAL_AS void*)(Ag0 + kk),
                                         (LDS_AS void*)&Als[ad0], 16, 0, 0);
        __builtin_amdgcn_global_load_lds((const GLOBAL_AS void*)(Ag1 + kk),
                                         (LDS_AS void*)&Als[ad1], 16, 0, 0);
        __builtin_amdgcn_global_load_lds((const GLOBAL_AS void*)(Bg0 + kk),
                                         (LDS_AS void*)&Bls[ad0], 16, 0, 0);
        __builtin_amdgcn_global_load_lds((const GLOBAL_AS void*)(Bg1 + kk),
                                         (LDS_AS void*)&Bls[ad1], 16, 0, 0);
        __syncthreads();
        bf16x8 af[2][2], bfv[2][2];
        #pragma unroll
        for (int hh = 0; hh < 2; ++hh) {
            #pragma unroll
            for (int m = 0; m < 2; ++m)
                af[m][hh] = *(const bf16x8*)&Als[hh * 2048 + (wr * 32 + m * 16 + fr) * 32 + ks];
            #pragma unroll
            for (int n = 0; n < 2; ++n)
                bfv[n][hh] = *(const bf16x8*)&Bls[hh * 2048 + (wc * 32 + n * 16 + fr) * 32 + ks];
        }
        #pragma unroll
        for (int hh = 0; hh < 2; ++hh)
            #pragma unroll
            for (int m = 0; m < 2; ++m)
                #pragma unroll
                for (int n = 0; n < 2; ++n)
                    acc[m][n] = __builtin_amdgcn_mfma_f32_16x16x32_bf16(
                        af[m][hh], bfv[n][hh], acc[m][n], 0, 0, 0);
        __syncthreads();
    }

    float bsv[2];
    #pragma unroll
    for (int n = 0; n < 2; ++n) bsv[n] = HASB ? bias[n0 + wc * 32 + n * 16 + fr] : 0.f;
    #pragma unroll
    for (int m = 0; m < 2; ++m) {
        #pragma unroll
        for (int r = 0; r < 4; ++r) {
            const int grow = m0 + wr * 32 + m * 16 + fq * 4 + r;
            const long rowoff = (long)grow * ldc + n0 + wc * 32 + fr;
            #pragma unroll
            for (int n = 0; n < 2; ++n) {
                float v = acc[m][n][r] + bsv[n];
                if (ACT) v = gelu_f(v);
                const long off = rowoff + n * 16;
                if (ACCF) v += bf2f(Cp[off]);
                Cp[off] = f2bf(v);
            }
        }
    }
}

template<int ACT, int HASB, int ACCF>
__global__ __launch_bounds__(256)
void gemm64(const ushort* __restrict__ A, const ushort* __restrict__ BT,
            const float* __restrict__ bias, ushort* __restrict__ Cout,
            int Kd, int lda, int ldb, int ldc,
            long sA, long sBT, long sC)
{
    __shared__ ushort Als[2 * 2048];
    __shared__ ushort Bls[2 * 2048];
    const int bz = blockIdx.z;
    gemm64_core<ACT, HASB, ACCF>(A + (long)bz * sA, BT + (long)bz * sBT, bias,
                                 Cout + (long)bz * sC, Kd, lda, ldb, ldc,
                                 blockIdx.x * 64, blockIdx.y * 64, Als, Bls);
}

// merged q + apkv: grid (512, 5). y==0 -> apkv block (x -> mx,ny,b); y>0 -> q tile.
// apkv blocks (32 K-iters) get the lowest linear indices so they start first.
__global__ __launch_bounds__(256)
void gemm_qap(const ushort* __restrict__ abf, const ushort* __restrict__ WqT,
              ushort* __restrict__ qbf, const ushort* __restrict__ EkvT,
              const ushort* __restrict__ aT, ushort* __restrict__ apkv)
{
    __shared__ ushort Als[2 * 2048];
    __shared__ ushort Bls[2 * 2048];
    if (blockIdx.y == 0) {
        const int mx = blockIdx.x & 7, ny = (blockIdx.x >> 3) & 3, b = blockIdx.x >> 5;
        gemm64_core<0, 0, 0>(EkvT, aT + (long)b * 524288, nullptr,
                             apkv + (long)b * 131072, 2048, 2048, 2048, 256,
                             mx * 64, ny * 64, Als, Bls);
    } else {
        gemm64_core<0, 0, 0>(abf, WqT, nullptr, qbf, 256, 256, 256, 256,
                             blockIdx.x * 64, (blockIdx.y - 1) * 64, Als, Bls);
    }
}

// merged kp/vpT: grid (4,4,32); z<16 -> kp[b] = apk[b]@Wk; z>=16 -> vpT[b] = Wv^T@apv[b]^T
__global__ __launch_bounds__(256)
void gemm_kv(const ushort* __restrict__ apkv, const ushort* __restrict__ WkT,
             const ushort* __restrict__ WvT, ushort* __restrict__ kp,
             ushort* __restrict__ vpT)
{
    __shared__ ushort Als[2 * 2048];
    __shared__ ushort Bls[2 * 2048];
    const int z = blockIdx.z, b = z & 15, op = z >> 4;
    const ushort* Ab; const ushort* Bb; ushort* Cp;
    if (op == 0) {
        Ab = apkv + (long)b * 131072; Bb = WkT; Cp = kp + (long)b * 65536;
    } else {
        Ab = WvT; Bb = apkv + 65536 + (long)b * 131072; Cp = vpT + (long)b * 65536;
    }
    gemm64_core<0, 0, 0>(Ab, Bb, nullptr, Cp, 256, 256, 256, 256,
                         blockIdx.x * 64, blockIdx.y * 64, Als, Bls);
}

// ---------------- fused MFMA attention, swapped-operand, P in registers ----------------
__global__ __launch_bounds__(256)
void attn_mfma2(const ushort* __restrict__ Q, const ushort* __restrict__ Kp,
                const ushort* __restrict__ VpT, ushort* __restrict__ O)
{
    __shared__ ushort Kls[256 * 40];
    __shared__ ushort Vls[32 * 264];
    const int qt = blockIdx.x, h = blockIdx.y, b = blockIdx.z;
    const int n0 = qt * 64;
    const int t = threadIdx.x, w = t >> 6, l = t & 63;
    const int fr = l & 15, fq = l >> 4;

    #pragma unroll
    for (int it = 0; it < 4; ++it) {
        const int r = (t >> 2) + it * 64, c = (t & 3) * 8;
        *(float4*)&Kls[r * 40 + c] =
            *(const float4*)&Kp[((long)(b * 256 + r)) * 256 + h * 32 + c];
    }
    {
        const int r = t >> 3, c0 = (t & 7) * 32;
        const ushort* src = VpT + ((long)(b * 256 + h * 32 + r)) * 256 + c0;
        #pragma unroll
        for (int j = 0; j < 4; ++j)
            *(float4*)&Vls[r * 264 + c0 + j * 8] = *(const float4*)(src + j * 8);
    }
    const bf16x8 bq = *(const bf16x8*)
        &Q[((long)(b * 2048 + n0 + w * 16 + fr)) * 256 + h * 32 + fq * 8];
    __syncthreads();

    f32x4 s[16];
    #pragma unroll
    for (int n = 0; n < 16; ++n) {
        const bf16x8 ak = *(const bf16x8*)&Kls[(n * 16 + fr) * 40 + fq * 8];
        s[n] = __builtin_amdgcn_mfma_f32_16x16x32_bf16(ak, bq, f32x4{0.f,0.f,0.f,0.f}, 0, 0, 0);
    }
    const float scale = 0.17677669529663687f;
    float mx = -1e30f;
    #pragma unroll
    for (int n = 0; n < 16; ++n)
        #pragma unroll
        for (int r = 0; r < 4; ++r) { s[n][r] *= scale; mx = fmaxf(mx, s[n][r]); }
    mx = fmaxf(mx, __shfl_xor(mx, 16));
    mx = fmaxf(mx, __shfl_xor(mx, 32));
    float sm = 0.f;
    unsigned int p[16][2];
    #pragma unroll
    for (int n = 0; n < 16; ++n) {
        float e0 = __expf(s[n][0] - mx), e1 = __expf(s[n][1] - mx);
        float e2 = __expf(s[n][2] - mx), e3 = __expf(s[n][3] - mx);
        sm += (e0 + e1) + (e2 + e3);
        p[n][0] = ((unsigned int)f2bf(e1) << 16) | f2bf(e0);
        p[n][1] = ((unsigned int)f2bf(e3) << 16) | f2bf(e2);
    }
    sm += __shfl_xor(sm, 16);
    sm += __shfl_xor(sm, 32);

    const int fqa = fq & 1, fqb = fq >> 1;
    f32x4 o[2] = {f32x4{0.f,0.f,0.f,0.f}, f32x4{0.f,0.f,0.f,0.f}};
    #pragma unroll
    for (int kk = 0; kk < 8; ++kk) {
        u32x4 bw;
        #pragma unroll
        for (int wd = 0; wd < 4; ++wd) {
            const int srcl = fr + ((2 * fqa + (wd >> 1)) << 4);
            const unsigned int v0 = __shfl((int)p[2 * kk][wd & 1], srcl);
            const unsigned int v1 = __shfl((int)p[2 * kk + 1][wd & 1], srcl);
            bw[wd] = fqb ? v1 : v0;
        }
        const bf16x8 breg = __builtin_bit_cast(bf16x8, bw);
        #pragma unroll
        for (int nd = 0; nd < 2; ++nd) {
            const bf16x8 av = *(const bf16x8*)&Vls[(nd * 16 + fr) * 264 + kk * 32 + fq * 8];
            o[nd] = __builtin_amdgcn_mfma_f32_16x16x32_bf16(av, breg, o[nd], 0, 0, 0);
        }
    }
    const float inv = 1.0f / sm;
    const long rowbase = ((long)(b * 2048 + n0 + w * 16 + fr)) * 256 + h * 32;
    #pragma unroll
    for (int nd = 0; nd < 2; ++nd) {
        ushort4 y;
        y.x = f2bf(o[nd][0] * inv); y.y = f2bf(o[nd][1] * inv);
        y.z = f2bf(o[nd][2] * inv); y.w = f2bf(o[nd][3] * inv);
        *(ushort4*)&O[rowbase + nd * 16 + fq * 4] = y;
    }
}

// ---------------- final head (bf16 h) ----------------
__global__ __launch_bounds__(256)
void out_kernel(const ushort* __restrict__ H, const float* __restrict__ Wout,
                const float* __restrict__ bout, float* __restrict__ out)
{
    const int row = blockIdx.x * 4 + (threadIdx.x >> 6);
    const int lane = threadIdx.x & 63;
    const ushort4 hu = *(const ushort4*)&H[(long)row * 256 + lane * 4];
    float4 wv = *(const float4*)&Wout[lane * 4];
    float s = bf2f(hu.x) * wv.x + bf2f(hu.y) * wv.y +
              bf2f(hu.z) * wv.z + bf2f(hu.w) * wv.w;
    #pragma unroll
    for (int m = 32; m >= 1; m >>= 1) s += __shfl_xor(s, m);
    if (lane == 0) out[row] = s + bout[0];
}

extern "C" void kernel_launch(void* const* d_in, const int* in_sizes, int n_in,
                              void* d_out, int out_size, void* d_ws, size_t ws_size,
                              hipStream_t stream)
{
    const float* x    = (const float*)d_in[0];
    const float* Wemb = (const float*)d_in[1];
    const float* bemb = (const float*)d_in[2];
    const float* pos  = (const float*)d_in[3];
    const float* ln0g = (const float*)d_in[4];
    const float* ln0b = (const float*)d_in[5];
    const float* ln1g = (const float*)d_in[6];
    const float* ln1b = (const float*)d_in[7];
    const float* Wq   = (const float*)d_in[8];
    const float* Wk   = (const float*)d_in[9];
    const float* Wv   = (const float*)d_in[10];
    const float* Ek   = (const float*)d_in[11];
    const float* Ev   = (const float*)d_in[12];
    const float* Wo   = (const float*)d_in[13];
    const float* bo   = (const float*)d_in[14];
    const float* ln2g = (const float*)d_in[15];
    const float* ln2b = (const float*)d_in[16];
    const float* W1   = (const float*)d_in[17];
    const float* b1   = (const float*)d_in[18];
    const float* W2   = (const float*)d_in[19];
    const float* b2   = (const float*)d_in[20];
    const float* Wout = (const float*)d_in[21];
    const float* bout = (const float*)d_in[22];

    char* ws = (char*)d_ws;
    ushort* h    = (ushort*)(ws + 0);                  // bf16 [32768,256]
    ushort* abf  = (ushort*)(ws + 33554432L);
    ushort* aT   = (ushort*)(ws + 50331648L);
    ushort* kp   = (ushort*)(ws + 67108864L);
    ushort* vpT  = (ushort*)(ws + 69206016L);
    ushort* apkv = (ushort*)(ws + 71303168L);
    ushort* qbf  = (ushort*)(ws + 100663296L);
    ushort* hid  = (ushort*)(ws + 50331648L);
    ushort* WT   = (ushort*)(ws + 117440512L);
    ushort* WqT  = WT;
    ushort* WkT  = WT + 262144;
    ushort* WvT  = WT + 524288;
    ushort* WoT  = WT + 786432;
    ushort* W1T  = WT + 1048576;
    ushort* W2T  = WT + 2097152;
    ushort* EkvT = WT + 3145728;
    float* outp = (float*)d_out;

    transpose_cast<<<dim3(8, 8, 4), 256, 0, stream>>>(Wq, WqT, 256, 256, 65536, 65536);
    transpose_cast<<<dim3(8, 8, 4), 256, 0, stream>>>(Wk, WkT, 256, 256, 65536, 65536);
    transpose_cast<<<dim3(8, 8, 4), 256, 0, stream>>>(Wv, WvT, 256, 256, 65536, 65536);
    transpose_cast<<<dim3(8, 8, 4), 256, 0, stream>>>(Wo, WoT, 256, 256, 65536, 65536);
    transpose_cast<<<dim3(32, 8, 4), 256, 0, stream>>>(W1, W1T, 256, 1024, 262144, 262144);
    transpose_cast<<<dim3(8, 32, 4), 256, 0, stream>>>(W2, W2T, 1024, 256, 262144, 262144);
    transpose_cast<<<dim3(8, 64, 4), 256, 0, stream>>>(Ek, EkvT, 2048, 256, 524288, 1048576);
    transpose_cast<<<dim3(8, 64, 4), 256, 0, stream>>>(Ev, EkvT + 524288, 2048, 256, 524288, 1048576);

    embed_ln3<<<1024, 256, 0, stream>>>(x, Wemb, bemb, pos, ln0g, ln0b, h);
    ln_tr<<<1024, 256, 0, stream>>>(h, ln1g, ln1b, abf, aT);

    for (int i = 0; i < 4; ++i) {
        const ushort* WqT_i = WqT + i * 65536;
        const ushort* WkT_i = WkT + i * 65536;
        const ushort* WvT_i = WvT + i * 65536;
        const ushort* WoT_i = WoT + i * 65536;
        const ushort* W1T_i = W1T + i * 262144;
        const ushort* W2T_i = W2T + i * 262144;
        const ushort* EkvT_i = EkvT + (long)i * 1048576;

        // q = a@Wq  and  apkv[b] = [Ek^T;Ev^T]@a[b] — merged dispatch (2560 blocks)
        gemm_qap<<<dim3(512, 5, 1), 256, 0, stream>>>(abf, WqT_i, qbf, EkvT_i, aT, apkv);
        // kp[b] = apk[b]@Wk  and  vpT[b] = Wv^T@apv[b]^T — merged dispatch
        gemm_kv<<<dim3(4, 4, 32), 256, 0, stream>>>(apkv, WkT_i, WvT_i, kp, vpT);
        // fused MFMA attention -> abf
        attn_mfma2<<<dim3(32, 8, 16), 256, 0, stream>>>(qbf, kp, vpT, abf);
        // h += attnout @ Wo + bo (bf16 RMW)
        gemm64<0,1,1><<<dim3(512, 4, 1), 256, 0, stream>>>(abf, WoT_i, bo + i * 256, h,
            256, 256, 256, 256, 0, 0, 0);
        // abf = LN2(h)
        ln_bf<<<8192, 256, 0, stream>>>(h, ln2g + i * 256, ln2b + i * 256, abf);
        // hid = gelu(a @ W1 + b1)
        gemm64<1,1,0><<<dim3(512, 16, 1), 256, 0, stream>>>(abf, W1T_i,
            b1 + (long)i * 1024, hid, 256, 256, 256, 1024, 0, 0, 0);
        // h += hid @ W2 + b2 (bf16 RMW)
        gemm64<0,1,1><<<dim3(512, 4, 1), 256, 0, stream>>>(hid, W2T_i, b2 + i * 256, h,
            1024, 1024, 1024, 256, 0, 0, 0);
        if (i < 3)
            ln_tr<<<1024, 256, 0, stream>>>(h, ln1g + (i + 1) * 256,
                ln1b + (i + 1) * 256, abf, aT);
    }
    out_kernel<<<8192, 256, 0, stream>>>(h, Wout, bout, outp);
}